// Round 18
// baseline (63.234 us; speedup 1.0000x reference)
//
#include <hip/hip_runtime.h>
#include <hip/hip_fp16.h>

// vol:  [B=8, D=64, H=128, W=128, C=2] f32
// flow: [B, D, H, W, 3] f32 (displacements)
// out:  [B, D, H, W, C] f32
//
// R18 = R17 (256 persistent blocks, fp16-packed window, top-of-iter reg
// prefetch) with a 16-slot circular window -> ONE barrier per iter.
//  - slot = plane & 15. Window readable [d0-4, d0+7]; writes target planes
//    d0+8..d0+11. 16 consecutive plane numbers -> distinct mod-16 residues
//    -> write slots disjoint from read slots WITHIN the iter, so ds_writes
//    overlap the gather phase and only one end-of-iter barrier is needed.
//    Across iters the barrier publishes new planes + fences slot reuse.
//  - LDS: 16 slots x 12 rows x 130 uints (uint = half2(x,y)) = 99,840 B.
//  - gather: 4 x ds_read2_b32 per voxel; combine in f32.
//  - |jitter| > halo (P~1e-4): exec-masked exact f32 global fallback.

typedef float f32x4 __attribute__((ext_vector_type(4)));
typedef f32x4 __attribute__((aligned(8))) f32x4a;

#define ROWU   130                 // uints per row (128 data + 2 pad)
#define SLOTU  (12 * ROWU)         // 1560 uints per plane-slot
#define NSLOT  16

__device__ __forceinline__ void sample_store(
    const float* __restrict__ vb, const uint* lds_u,
    float f0, float f1, float f2,
    int d, int h, int w, int dbase, int hbase,
    float* __restrict__ out, size_t vox)
{
    float cd = fminf(fmaxf((float)d + f0, 0.0f), 63.0f);
    float ch = fminf(fmaxf((float)h + f1, 0.0f), 127.0f);
    float cw = fminf(fmaxf((float)w + f2, 0.0f), 127.0f);
    int ld = (int)cd; ld = (ld > 62) ? 62 : ld;
    int lh = (int)ch; lh = (lh > 126) ? 126 : lh;
    int lw = (int)cw; lw = (lw > 126) ? 126 : lw;
    const float wd = cd - (float)ld;
    const float wh = ch - (float)lh;
    const float ww = cw - (float)lw;
    const int i_d = ld - dbase;   // LDS path: <= 10 (ld+1 in window)
    const int i_h = lh - hbase;   // <= 10

    float x00, y00, x00r, y00r, x01, y01, x01r, y01r;
    float x10, y10, x10r, y10r, x11, y11, x11r, y11r;
    if (__builtin_expect(((unsigned)i_d <= 10u) & ((unsigned)i_h <= 10u), 1)) {
        const int m0 = ld & 15;            // slot = plane mod 16
        const int m1 = (ld + 1) & 15;
        const int e0 = m0 * SLOTU + i_h * ROWU + lw;
        const int e1 = m1 * SLOTU + i_h * ROWU + lw;
        const uint uA0 = lds_u[e0],        uA1 = lds_u[e0 + 1];        // read2
        const uint uB0 = lds_u[e0 + ROWU], uB1 = lds_u[e0 + ROWU + 1]; // read2
        const uint uC0 = lds_u[e1],        uC1 = lds_u[e1 + 1];        // read2
        const uint uD0 = lds_u[e1 + ROWU], uD1 = lds_u[e1 + ROWU + 1]; // read2
        __half2 h2;
        h2 = *(const __half2*)&uA0; x00  = __low2float(h2); y00  = __high2float(h2);
        h2 = *(const __half2*)&uA1; x00r = __low2float(h2); y00r = __high2float(h2);
        h2 = *(const __half2*)&uB0; x01  = __low2float(h2); y01  = __high2float(h2);
        h2 = *(const __half2*)&uB1; x01r = __low2float(h2); y01r = __high2float(h2);
        h2 = *(const __half2*)&uC0; x10  = __low2float(h2); y10  = __high2float(h2);
        h2 = *(const __half2*)&uC1; x10r = __low2float(h2); y10r = __high2float(h2);
        h2 = *(const __half2*)&uD0; x11  = __low2float(h2); y11  = __high2float(h2);
        h2 = *(const __half2*)&uD1; x11r = __low2float(h2); y11r = __high2float(h2);
    } else {
        const int o = (ld << 15) + (lh << 8) + (lw << 1);
        const f32x4 a00 = *(const f32x4a*)(vb + o);
        const f32x4 a01 = *(const f32x4a*)(vb + o + 256);
        const f32x4 a10 = *(const f32x4a*)(vb + o + 32768);
        const f32x4 a11 = *(const f32x4a*)(vb + o + 33024);
        x00 = a00.x; y00 = a00.y; x00r = a00.z; y00r = a00.w;
        x01 = a01.x; y01 = a01.y; x01r = a01.z; y01r = a01.w;
        x10 = a10.x; y10 = a10.y; x10r = a10.z; y10r = a10.w;
        x11 = a11.x; y11 = a11.y; x11r = a11.z; y11r = a11.w;
    }

    const float wd0 = 1.0f - wd, wh0 = 1.0f - wh;
    const float ww1 = ww, ww0 = 1.0f - ww;
    const float w00 = wd0 * wh0, w01 = wd0 * wh;
    const float w10 = wd * wh0,  w11 = wd * wh;

    const float ox = (x00 * w00 + x01 * w01 + x10 * w10 + x11 * w11) * ww0
                   + (x00r * w00 + x01r * w01 + x10r * w10 + x11r * w11) * ww1;
    const float oy = (y00 * w00 + y01 * w01 + y10 * w10 + y11 * w11) * ww0
                   + (y00r * w00 + y01r * w01 + y10r * w10 + y11r * w11) * ww1;

    *(float2*)(out + vox * 2) = make_float2(ox, oy);
}

__global__ __launch_bounds__(1024, 4) void st_one_bar_kernel(
    const float* __restrict__ vol,
    const float* __restrict__ flow,
    float* __restrict__ out)
{
    __shared__ uint lds_u[NSLOT * SLOTU];   // 99,840 B (1 block/CU)

    const int t   = threadIdx.x;
    const int bid = blockIdx.x;             // b*32 + htile
    const int h0    = (bid & 31) << 2;
    const int b     = bid >> 5;
    const int hbase = h0 - 4;

    const float* vb = vol + ((size_t)b << 21);

    const int lane = t & 63;
    const int wid  = t >> 6;        // 0..15
    const int dr   = wid >> 2;      // 0..3: d offset within tile
    const int hh   = h0 + (wid & 3);

    // ---- initial stage: planes -4..7 -> slots (plane&15) = (i_d+12)&15 ----
    {
#pragma unroll
        for (int j = 0; j < 9; ++j) {
            const int c   = t + (j << 10);         // 0..9215
            const int s   = c >> 6, q = c & 63;    // row-slot, 16B chunk
            const int i_d = s / 12, i_h = s - i_d * 12;
            const int gd  = max(i_d - 4, 0);
            const int gh  = min(max(hbase + i_h, 0), 127);
            const f32x4 v = *(const f32x4*)(vb + ((((size_t)gd << 7) + gh) << 8) + (q << 2));
            const int sl  = (i_d + 12) & 15;       // plane (i_d-4) mod 16
            const __half2 ha = __floats2half2_rn(v.x, v.y);
            const __half2 hb = __floats2half2_rn(v.z, v.w);
            uint2 pk; pk.x = *(const uint*)&ha; pk.y = *(const uint*)&hb;
            *(uint2*)&lds_u[sl * SLOTU + i_h * ROWU + (q << 1)] = pk;
        }
    }

    // prologue flow (dt=0)
    float cfA0, cfA1, cfA2, cfB0, cfB1, cfB2;
    {
        const size_t rowbase = ((((size_t)((b << 6) | dr) << 7) | hh) << 7);
        const float* fA = flow + (rowbase + lane) * 3;
        cfA0 = fA[0]; cfA1 = fA[1]; cfA2 = fA[2];
        const float* fB = flow + (rowbase + lane + 64) * 3;
        cfB0 = fB[0]; cfB1 = fB[1]; cfB2 = fB[2];
    }
    __syncthreads();

    for (int dt = 0; dt < 16; ++dt) {
        const int d0    = dt << 2;
        const int dbase = d0 - 4;
        const int d     = d0 + dr;
        const size_t rowbase = ((((size_t)((b << 6) | d) << 7) | hh) << 7);
        const size_t voxA = rowbase + lane;

        // ---- prefetch next-iter staging (3 f32x4) + flow (6 f32) ----
        f32x4 s0, s1, s2;
        int   le0 = 0, le1 = 0, le2 = 0;
        float nfA0, nfA1, nfA2, nfB0, nfB1, nfB2;
        if (dt < 15) {
#define ISSUE_ST(K, VV, EE)                                                      \
            {                                                                    \
                const int c = t + ((K) << 10);                                   \
                const int row = c >> 6, q = c & 63;                              \
                const int i_d4 = row / 12, i_h = row - i_d4 * 12;                \
                const int p  = d0 + 8 + i_d4;      /* new planes d0+8..d0+11 */  \
                const int gd = (p > 63) ? 63 : p;                                \
                const int gh = min(max(hbase + i_h, 0), 127);                    \
                VV = *(const f32x4*)(vb + ((((size_t)gd << 7) + gh) << 8) + (q << 2)); \
                EE = (p & 15) * SLOTU + i_h * ROWU + (q << 1);                   \
            }
            ISSUE_ST(0, s0, le0) ISSUE_ST(1, s1, le1) ISSUE_ST(2, s2, le2)
#undef ISSUE_ST
            const int dn = d + 4;
            const size_t rbn = ((((size_t)((b << 6) | dn) << 7) | hh) << 7);
            const float* fA = flow + (rbn + lane) * 3;
            nfA0 = fA[0]; nfA1 = fA[1]; nfA2 = fA[2];
            const float* fB = flow + (rbn + lane + 64) * 3;
            nfB0 = fB[0]; nfB1 = fB[1]; nfB2 = fB[2];
            __builtin_amdgcn_sched_barrier(0);   // pin prefetch above gather
        }

        // ---- gather current tile (reads slots of planes d0-4..d0+7) ----
        sample_store(vb, lds_u, cfA0, cfA1, cfA2, d, hh, lane,
                     dbase, hbase, out, voxA);
        sample_store(vb, lds_u, cfB0, cfB1, cfB2, d, hh, lane + 64,
                     dbase, hbase, out, voxA + 64);

        // ---- write new planes (slots disjoint from this iter's reads) ----
        if (dt < 15) {
#define WRPK(VV, EE)                                                             \
            {                                                                    \
                const __half2 ha = __floats2half2_rn(VV.x, VV.y);                \
                const __half2 hb = __floats2half2_rn(VV.z, VV.w);                \
                uint2 pk; pk.x = *(const uint*)&ha; pk.y = *(const uint*)&hb;    \
                *(uint2*)&lds_u[EE] = pk;                                        \
            }
            WRPK(s0, le0) WRPK(s1, le1) WRPK(s2, le2)
#undef WRPK
            __syncthreads();   // single barrier: publish planes d0+8..d0+11
            cfA0 = nfA0; cfA1 = nfA1; cfA2 = nfA2;
            cfB0 = nfB0; cfB1 = nfB1; cfB2 = nfB2;
        }
    }
}

extern "C" void kernel_launch(void* const* d_in, const int* in_sizes, int n_in,
                              void* d_out, int out_size, void* d_ws, size_t ws_size,
                              hipStream_t stream) {
    const float* vol  = (const float*)d_in[0];
    const float* flow = (const float*)d_in[1];
    float* out = (float*)d_out;

    // 8 batches x 32 h-tiles = 256 persistent blocks (1 per CU)
    hipLaunchKernelGGL(st_one_bar_kernel, dim3(256), dim3(1024), 0, stream,
                       vol, flow, out);
}